// Round 3
// baseline (263.466 us; speedup 1.0000x reference)
//
#include <hip/hip_runtime.h>

// Depthwise separable 4x4 FIR blur (StyleGAN2 upfirdn2d, up=down=1, pad=(2,2)).
// x: [B,C,256,256] f32, kernel: [4,4] f32 separable, out: [B,C,257,257] f32.
//
// out[oh,ow] = sum_i v[i] * H[oh+1-i],  H[r][c] = sum_j w[j]*x[r][c+1-j]
// w[j] = k2d[0][j], v[i] = k2d[i][0]/k2d[0][0] (v0 == 1).
//
// Block = one plane (4 waves = 4 row-strips of 64/64/64/65). Each lane owns 4
// output columns; per input row it issues exactly ONE float4 load — halo
// columns come from neighbor lanes via __shfl (ds_bpermute). Vertical reuse in
// a 4-deep register ring; raw input row prefetched one full iteration ahead.
// Grid = 2048 blocks = 8192 waves = exactly full machine residency.

#define IW 256
#define IH 256
#define OW 257
#define OH 257

typedef float f4u __attribute__((vector_size(16), aligned(4)));  // 4B-aligned store

__global__ __launch_bounds__(256) void blur_fir_kernel(
    const float* __restrict__ x,
    const float* __restrict__ k2d,
    float* __restrict__ out)
{
    const int tid   = threadIdx.x;
    const int cg    = tid & 63;            // lane = column group: cols [4cg, 4cg+4)
    const int strip = tid >> 6;            // 0..3 (wave = strip)
    const int plane = blockIdx.x;

    const float w0 = k2d[0], w1 = k2d[1], w2 = k2d[2], w3 = k2d[3];
    const float inv = 1.0f / w0;
    const float v1 = k2d[4] * inv, v2 = k2d[8] * inv, v3 = k2d[12] * inv;

    const int   c0 = cg << 2;
    const float mL = (cg > 0)  ? 1.0f : 0.0f;
    const float mR = (cg < 63) ? 1.0f : 0.0f;
    const int   lm = (cg > 0)  ? cg - 1 : 0;   // neighbor-left lane
    const int   lp = (cg < 63) ? cg + 1 : 63;  // neighbor-right lane

    const float* xp = x + ((size_t)plane << 16);
    const int r0    = strip << 6;
    const int nrows = (strip == 3) ? 65 : 64;  // rows 0..255 + row 256

    auto loadraw = [&](int r) -> float4 {
        int rr = min(max(r, 0), IH - 1);       // clamp: OOB rows masked later
        return *(const float4*)(xp + (rr << 8) + c0);
    };
    auto hcomb = [&](float4 Bv, int r, float4& h, float& h4) {
        float rm = (r >= 0 && r < IH) ? 1.0f : 0.0f;
        float lx = __shfl(Bv.z, lm, 64) * mL;  // x[r][c0-2]
        float ly = __shfl(Bv.w, lm, 64) * mL;  // x[r][c0-1]
        float rv = __shfl(Bv.x, lp, 64) * mR;  // x[r][c0+4]
        h.x = w0 * Bv.y + w1 * Bv.x + w2 * ly   + w3 * lx;
        h.y = w0 * Bv.z + w1 * Bv.y + w2 * Bv.x + w3 * ly;
        h.z = w0 * Bv.w + w1 * Bv.z + w2 * Bv.y + w3 * Bv.x;
        h.w = w0 * rv   + w1 * Bv.w + w2 * Bv.z + w3 * Bv.y;
        h4  = w2 * Bv.w + w3 * Bv.z;           // out col 256 (lane 63 only used)
        h.x *= rm; h.y *= rm; h.z *= rm; h.w *= rm; h4 *= rm;
    };

    // Prime ring: H(r0-2)..H(r0+1), plus raw row r0+2 in flight.
    float4 hm2, hm1, h0, hp1;
    float  sm2, sm1, s0, sp1;
    { float4 B = loadraw(r0 - 2); hcomb(B, r0 - 2, hm2, sm2); }
    { float4 B = loadraw(r0 - 1); hcomb(B, r0 - 1, hm1, sm1); }
    { float4 B = loadraw(r0    ); hcomb(B, r0    , h0,  s0 ); }
    { float4 B = loadraw(r0 + 1); hcomb(B, r0 + 1, hp1, sp1); }
    float4 Bp = loadraw(r0 + 2);

    float* op = out + (size_t)plane * (OW * OH) + (size_t)r0 * OW + c0;
    const bool last = (cg == 63);

    #pragma unroll 2
    for (int i = 0; i < nrows; ++i) {
        float4 Bn = loadraw(r0 + i + 3);       // prefetch: consumed next iter

        float4 res;
        res.x = hp1.x + v1 * h0.x + v2 * hm1.x + v3 * hm2.x;
        res.y = hp1.y + v1 * h0.y + v2 * hm1.y + v3 * hm2.y;
        res.z = hp1.z + v1 * h0.z + v2 * hm1.z + v3 * hm2.z;
        res.w = hp1.w + v1 * h0.w + v2 * hm1.w + v3 * hm2.w;
        *(f4u*)op = (f4u){res.x, res.y, res.z, res.w};
        if (last) op[4] = sp1 + v1 * s0 + v2 * sm1 + v3 * sm2;
        op += OW;

        float4 hn; float sn;
        hcomb(Bp, r0 + i + 2, hn, sn);         // uses row loaded LAST iter
        hm2 = hm1; hm1 = h0; h0 = hp1; hp1 = hn;
        sm2 = sm1; sm1 = s0; s0 = sp1; sp1 = sn;
        Bp = Bn;
    }
}

extern "C" void kernel_launch(void* const* d_in, const int* in_sizes, int n_in,
                              void* d_out, int out_size, void* d_ws, size_t ws_size,
                              hipStream_t stream) {
    const float* x   = (const float*)d_in[0];
    const float* k2d = (const float*)d_in[1];
    float* out = (float*)d_out;

    int nplanes = in_sizes[0] >> 16;           // B*C = 2048
    blur_fir_kernel<<<nplanes, 256, 0, stream>>>(x, k2d, out);
}